// Round 16
// baseline (226.445 us; speedup 1.0000x reference)
//
#include <hip/hip_runtime.h>
#include <math.h>

// B*S = 8192 tokens, K=8, N_BASIS=32, RANK=8, D_MODEL=256, D_HID=1024
// ws: wr f32 | h f32 | wrAh/wrAl | bf1h,bf1l,bf2h,bf2l | wfh,wfl  (~5.8 MB)
// fusedB v4 (65us) + all-16-wave tail. stageA v2: vectorized h-phase with
// bank-audited transposed layouts (r15's version had a 32-way conflict on the
// cA2-T store: j*64 stride ≡ 0 mod 32 banks — fixed via 68-stride + l-swizzle).

typedef unsigned short u16;
typedef unsigned int u32;
typedef __attribute__((ext_vector_type(8))) __bf16 bf16x8;
typedef __attribute__((ext_vector_type(4))) float f32x4;
typedef __attribute__((ext_vector_type(16))) float f32x16;
union ABCast { float4 f; bf16x8 v; };
union U4Cast { u32 u[4]; bf16x8 v; };
union BFBits { __bf16 b; u16 u; };
union Pack8 { u16 u[8]; float4 f; };

__device__ __forceinline__ float gelu_exact(float v) {
    return 0.5f * v * (1.0f + erff(v * 0.70710678118654752440f));
}
__device__ __forceinline__ u16 f2bf_bits(float f) { BFBits c; c.b = (__bf16)f; return c.u; }
__device__ __forceinline__ float bfbits2f(u16 u) { BFBits c; c.u = u; return (float)c.b; }

// ---------------- K1: routing -> wr f32 + wr A-frags (bf16 h/l) ----------------
__global__ __launch_bounds__(64) void k_route(
    const int* __restrict__ nidx, const float* __restrict__ nw,
    const float* __restrict__ recipes, float* __restrict__ wr_out,
    u16* __restrict__ wrAh, u16* __restrict__ wrAl)
{
    const int t = blockIdx.x * 64 + threadIdx.x;
    float acc[32];
#pragma unroll
    for (int n = 0; n < 32; n++) acc[n] = 0.f;
#pragma unroll
    for (int k = 0; k < 8; k++) {
        const int   id = nidx[t * 8 + k];
        const float wk = nw[t * 8 + k];
        const float4* row = (const float4*)(recipes + id * 32);
        float v[32];
#pragma unroll
        for (int q = 0; q < 8; q++) {
            float4 f = row[q];
            v[q*4+0] = f.x; v[q*4+1] = f.y; v[q*4+2] = f.z; v[q*4+3] = f.w;
        }
        float m = v[0];
#pragma unroll
        for (int n = 1; n < 32; n++) m = fmaxf(m, v[n]);
        float s = 0.f;
#pragma unroll
        for (int n = 0; n < 32; n++) { float e = expf(v[n] - m); v[n] = e; s += e; }
        const float iv = wk / s;
#pragma unroll
        for (int n = 0; n < 32; n++) acc[n] += v[n] * iv;
    }
    float4* o = (float4*)(wr_out + t * 32);
#pragma unroll
    for (int q = 0; q < 8; q++)
        o[q] = make_float4(acc[q*4+0], acc[q*4+1], acc[q*4+2], acc[q*4+3]);

    const int tg16 = t >> 4, tl = t & 15;
#pragma unroll
    for (int c = 0; c < 4; c++) {
        Pack8 ph, pl;
#pragma unroll
        for (int e = 0; e < 8; e++) {
            const float v = acc[c*8 + e];
            const u16 hb = f2bf_bits(v);
            ph.u[e] = hb;
            pl.u[e] = f2bf_bits(v - bfbits2f(hb));
        }
        const int lane = c * 16 + tl;
        *(float4*)(wrAh + (tg16*64 + lane)*8) = ph.f;
        *(float4*)(wrAl + (tg16*64 + lane)*8) = pl.f;
    }
}

// ---------------- K2: stage A  x[256] -> h[64], 8 tokens/block ----------------
// ph1: cA1 flat [i*64+r*8+k] into ca (1088-strided). ph2: temp in regs.
// ph3: temp-T -> tl[k*136 + j*8 + r] (reads 2-way, stores 4-way);
//      cA2-T -> ca[j*68 + ((l+j)&7)*8 + r] (reads 2-way, stores <=8-way).
// ph4: h = float4-over-r dot products (64 b128 reads vs 256 scalar before).
__global__ __launch_bounds__(512) void k_stageA(
    const float* __restrict__ x, const float* __restrict__ wr,
    const float* __restrict__ A1, const float* __restrict__ A2,
    float* __restrict__ h_out)
{
    __shared__ float ca[8 * 1088];
    __shared__ float tl[8 * 1088];
    const int tid = threadIdx.x;
    const int t0  = blockIdx.x * 8;

    // ---- ph1: build cA1 flat ----
    {
        const int e2 = tid * 2;
        float2 c[8];
#pragma unroll
        for (int tt = 0; tt < 8; tt++) c[tt] = make_float2(0.f, 0.f);
#pragma unroll 4
        for (int n = 0; n < 32; n++) {
            const float2 a = *(const float2*)(A1 + n * 1024 + e2);
#pragma unroll
            for (int tt = 0; tt < 8; tt++) {
                const float s = wr[(t0 + tt) * 32 + n];
                c[tt].x += s * a.x; c[tt].y += s * a.y;
            }
        }
#pragma unroll
        for (int tt = 0; tt < 8; tt++) *(float2*)(ca + tt * 1088 + e2) = c[tt];
    }
    __syncthreads();

    // ---- ph2: temp = x_fold . cA1, kept in regs ----
    const int t = tid >> 6, g = tid & 63, j = g >> 2, eh = g & 3;
    float tr[16];
    {
        float xr[16];
#pragma unroll
        for (int i = 0; i < 16; i++) xr[i] = x[(t0 + t) * 256 + i * 16 + j];
#pragma unroll
        for (int q = 0; q < 16; q++) tr[q] = 0.f;
#pragma unroll
        for (int i = 0; i < 16; i++) {
            const float xv = xr[i];
#pragma unroll
            for (int q = 0; q < 4; q++) {
                const float4 cv = *(const float4*)(ca + t * 1088 + i * 64 + eh * 16 + q * 4);
                tr[q*4+0] += xv * cv.x; tr[q*4+1] += xv * cv.y;
                tr[q*4+2] += xv * cv.z; tr[q*4+3] += xv * cv.w;
            }
        }
    }
    __syncthreads();   // all cA1 reads done -> ca reusable

    // ---- ph3: build cA2 -> cA2-T; store temp-T ----
    {
        const int e2 = tid * 2;
        const int rr = e2 >> 7, jj = (e2 >> 3) & 15, ll = e2 & 7;
        float2 c[8];
#pragma unroll
        for (int tt = 0; tt < 8; tt++) c[tt] = make_float2(0.f, 0.f);
#pragma unroll 4
        for (int n = 0; n < 32; n++) {
            const float2 a = *(const float2*)(A2 + n * 1024 + e2);
#pragma unroll
            for (int tt = 0; tt < 8; tt++) {
                const float s = wr[(t0 + tt) * 32 + n];
                c[tt].x += s * a.x; c[tt].y += s * a.y;
            }
        }
        const int sw0 = ((ll + 0 + jj) & 7), sw1 = ((ll + 1 + jj) & 7);
#pragma unroll
        for (int tt = 0; tt < 8; tt++) {
            ca[tt * 1088 + jj * 68 + sw0 * 8 + rr] = c[tt].x;
            ca[tt * 1088 + jj * 68 + sw1 * 8 + rr] = c[tt].y;
        }
        // temp-T: tr[q] is temp for (r = eh*2 + (q>>3), k = q&7) at column j
#pragma unroll
        for (int q = 0; q < 16; q++)
            tl[t * 1088 + (q & 7) * 136 + j * 8 + (eh * 2 + (q >> 3))] = tr[q];
    }
    __syncthreads();

    // ---- ph4: h[k*8+l] = sum_{j,r} tempT[k][j][r] * cA2T[j][swz(l)][r] ----
    {
        const int k = g >> 3, l = g & 7;
        float acc = 0.f;
#pragma unroll
        for (int j2 = 0; j2 < 16; j2++) {
            const int sw = (l + j2) & 7;
#pragma unroll
            for (int rq = 0; rq < 2; rq++) {
                const float4 a = *(const float4*)(tl + t * 1088 + k * 136 + j2 * 8 + rq * 4);
                const float4 b = *(const float4*)(ca + t * 1088 + j2 * 68 + sw * 8 + rq * 4);
                acc += a.x * b.x + a.y * b.y + a.z * b.z + a.w * b.w;
            }
        }
        h_out[(t0 + t) * 64 + g] = acc;
    }
}

// ---------------- K3: prep (bsplit + wsplit merged) ----------------
__global__ __launch_bounds__(256) void k_prep(
    const float* __restrict__ B1, const float* __restrict__ B2,
    u16* __restrict__ o1h, u16* __restrict__ o1l,
    u16* __restrict__ o2h, u16* __restrict__ o2l,
    const float* __restrict__ W, u16* __restrict__ wfh, u16* __restrict__ wfl)
{
    if (blockIdx.x < 64) {
        const int slot = blockIdx.x * 256 + threadIdx.x;   // 0..16383
        const int bank = slot >> 13, r = (slot >> 10) & 7, g = (slot >> 6) & 15, l = slot & 63;
        const int c = l & 15, nb = 8 * (l >> 4);
        const int base = (bank == 0)
            ? ((g >> 1) * 256 + r * 32 + (g & 1) * 16 + c)
            : (r * 256 + (g >> 1) * 32 + (g & 1) * 16 + c);
        const float* S = (bank ? B2 : B1) + base + nb * 2048;
        Pack8 ph, pl;
#pragma unroll
        for (int e = 0; e < 8; e++) {
            const float v = S[e * 2048];
            const u16 hb = f2bf_bits(v);
            ph.u[e] = hb;
            pl.u[e] = f2bf_bits(v - bfbits2f(hb));
        }
        const int d = ((r * 16 + g) * 64 + l) * 8;
        *(float4*)((bank ? o2h : o1h) + d) = ph.f;
        *(float4*)((bank ? o2l : o1l) + d) = pl.f;
    } else {
        const int slot = (blockIdx.x - 64) * 256 + threadIdx.x;   // 0..32767
        const int ng = slot >> 11, kc = (slot >> 6) & 31, l = slot & 63;
        const float* S = W + (kc * 32 + 8 * (l >> 4)) * 256 + ng * 16 + (l & 15);
        Pack8 ph, pl;
#pragma unroll
        for (int e = 0; e < 8; e++) {
            const float v = S[e * 256];
            const u16 hb = f2bf_bits(v);
            ph.u[e] = hb;
            pl.u[e] = f2bf_bits(v - bfbits2f(hb));
        }
        const int d = ((ng * 32 + kc) * 64 + l) * 8;
        *(float4*)(wfh + d) = ph.f;
        *(float4*)(wfl + d) = pl.f;
    }
}

// ---------------- K4: fused stageB + down-proj v4 (all-16-wave down-proj) -------
__global__ __launch_bounds__(1024, 2) void k_fusedB(
    const float* __restrict__ hin,
    const u16* __restrict__ wrAh, const u16* __restrict__ wrAl,
    const u16* __restrict__ bf1h, const u16* __restrict__ bf1l,
    const u16* __restrict__ bf2h, const u16* __restrict__ bf2l,
    const u16* __restrict__ wfh, const u16* __restrict__ wfl,
    const float* __restrict__ bias, float* __restrict__ y)
{
    __shared__ __align__(16) unsigned char smem[65536];
    float* stg1 = (float*)smem;            // [2][16][256] f32 = 32KB (cb1 dbuf)
    float* stg2 = stg1 + 8192;             // [2][16][256] f32 = 32KB (cb2 dbuf)
    u16* gAh = (u16*)smem;                 // [32][64][8] u16 (phase-2 reuse, 32KB)
    u16* gAl = gAh + 16384;                // (32KB..64KB)

    const int tid = threadIdx.x;
    const int l   = tid & 63;
    const int w   = tid >> 6;              // 0..15 = token
    const int tg  = blockIdx.x;            // 16-token group (grid 512)
    const int t0  = tg * 16;
    const int kP  = l & 31;                // out-k row (A) / out-l col (B,C)
    const int jh  = l >> 5;

    // h for this wave's token (quad-j per lane; r-invariant)
    float hreg[32];
#pragma unroll
    for (int i = 0; i < 8; i++)
#pragma unroll
        for (int jj = 0; jj < 4; jj++)
            hreg[i*4+jj] = hin[(t0 + w) * 64 + i * 8 + jh * 4 + jj];

    // wr A-frags (16-token group)
    ABCast cu;
    cu.f = *(const float4*)(wrAh + (tg * 64 + l) * 8); const bf16x8 wra_h = cu.v;
    cu.f = *(const float4*)(wrAl + (tg * 64 + l) * 8); const bf16x8 wra_l = cu.v;

    // BUILD role: waves 0-7 -> cb1 staging, 8-15 -> cb2 staging; 2 groups each
    const bool isB2 = (w >= 8);
    const u16* bsrc_h = isB2 ? bf2h : bf1h;
    const u16* bsrc_l = isB2 ? bf2l : bf1l;
    float* cstg = isB2 ? stg2 : stg1;
    const int g0 = (w & 7) * 2;

    f32x16 accw = {0.f,0.f,0.f,0.f,0.f,0.f,0.f,0.f,0.f,0.f,0.f,0.f,0.f,0.f,0.f,0.f};
    u32 Afh0=0,Afh1=0,Afh2=0,Afh3=0, Afl0=0,Afl1=0,Afl2=0,Afl3=0;
    u32 Bfh0=0,Bfh1=0,Bfh2=0,Bfh3=0, Bfl0=0,Bfl1=0,Bfl2=0,Bfl3=0;

    float4 pbh0, pbl0, pbh1, pbl1;
#define LOADB(R) { const int rb_=(R)*16;                                        \
    pbh0 = *(const float4*)(bsrc_h + ((rb_+g0+0)*64+l)*8);                      \
    pbl0 = *(const float4*)(bsrc_l + ((rb_+g0+0)*64+l)*8);                      \
    pbh1 = *(const float4*)(bsrc_h + ((rb_+g0+1)*64+l)*8);                      \
    pbl1 = *(const float4*)(bsrc_l + ((rb_+g0+1)*64+l)*8); }
#define BUILD(BSEL) {                                                           \
    ABCast ch_, cl_;                                                            \
    __builtin_amdgcn_s_setprio(1);                                              \
    ch_.f = pbh0; cl_.f = pbl0;                                                 \
    f32x4 cc = {0.f,0.f,0.f,0.f};                                               \
    cc = __builtin_amdgcn_mfma_f32_16x16x32_bf16(wra_h, ch_.v, cc, 0, 0, 0);    \
    cc = __builtin_amdgcn_mfma_f32_16x16x32_bf16(wra_h, cl_.v, cc, 0, 0, 0);    \
    cc = __builtin_amdgcn_mfma_f32_16x16x32_bf16(wra_l, ch_.v, cc, 0, 0, 0);    \
    ch_.f = pbh1; cl_.f = pbl1;                                                 \
    f32x4 cc2 = {0.f,0.f,0.f,0.f};                                              \
    cc2 = __builtin_amdgcn_mfma_f32_16x16x32_bf16(wra_h, ch_.v, cc2, 0, 0, 0);  \
    cc2 = __builtin_amdgcn_mfma_f32_16x16x32_bf16(wra_h, cl_.v, cc2, 0, 0, 0);  \
    cc2 = __builtin_amdgcn_mfma_f32_16x16x32_bf16(wra_l, ch_.v, cc2, 0, 0, 0);  \
    __builtin_amdgcn_s_setprio(0);                                              \
    { const int gg = g0;                                                        \
      float* cd = cstg + (BSEL)*4096 + (gg>>1)*32 + (gg&1)*16 + (l&15);         \
      _Pragma("unroll")                                                         \
      for (int rg = 0; rg < 4; rg++) cd[(4*(l>>4)+rg)*256] = cc[rg]; }          \
    { const int gg = g0 + 1;                                                    \
      float* cd = cstg + (BSEL)*4096 + (gg>>1)*32 + (gg&1)*16 + (l&15);         \
      _Pragma("unroll")                                                         \
      for (int rg = 0; rg < 4; rg++) cd[(4*(l>>4)+rg)*256] = cc2[rg]; } }

    // prologue: build r=0 into buf0, prefetch r=1
    LOADB(0);
    BUILD(0);
    LOADB(1);
    __syncthreads();

#pragma unroll 1
    for (int r = 0; r < 8; r++) {
        if (r < 7) {
            BUILD((r+1)&1);
            if (r < 6) LOADB(r+2);
        }

        // ---- P2: quad-j t2 in regs -> pack -> shfl swap -> A-frag capture ----
        {
            const float* c1b = stg1 + (r & 1) * 4096 + w * 256;
            float t0q=0.f, t1q=0.f, t2q=0.f, t3q=0.f;
#pragma unroll
            for (int i = 0; i < 8; i++) {
                const float cv = c1b[i * 32 + kP];
                t0q += hreg[i*4+0] * cv; t1q += hreg[i*4+1] * cv;
                t2q += hreg[i*4+2] * cv; t3q += hreg[i*4+3] * cv;
            }
            const u16 h0 = f2bf_bits(t0q), h1 = f2bf_bits(t1q),
                      h2 = f2bf_bits(t2q), h3 = f2bf_bits(t3q);
            const u16 q0 = f2bf_bits(t0q - bfbits2f(h0)), q1 = f2bf_bits(t1q - bfbits2f(h1)),
                      q2 = f2bf_bits(t2q - bfbits2f(h2)), q3 = f2bf_bits(t3q - bfbits2f(h3));
            const u32 th0 = (u32)h0 | ((u32)h1 << 16), th1 = (u32)h2 | ((u32)h3 << 16);
            const u32 tl0 = (u32)q0 | ((u32)q1 << 16), tl1 = (u32)q2 | ((u32)q3 << 16);
            const u32 ph0 = (u32)__shfl_xor((int)th0, 32);
            const u32 ph1 = (u32)__shfl_xor((int)th1, 32);
            const u32 pl0 = (u32)__shfl_xor((int)tl0, 32);
            const u32 pl1 = (u32)__shfl_xor((int)tl1, 32);
            const u32 a0 = jh ? ph0 : th0, a1 = jh ? ph1 : th1;
            const u32 a2 = jh ? th0 : ph0, a3 = jh ? th1 : ph1;
            const u32 b0 = jh ? pl0 : tl0, b1 = jh ? pl1 : tl1;
            const u32 b2 = jh ? tl0 : pl0, b3 = jh ? tl1 : pl1;
            if ((r & 1) == jh) {
                Afh0 = a0; Afh1 = a1; Afh2 = a2; Afh3 = a3;
                Afl0 = b0; Afl1 = b1; Afl2 = b2; Afl3 = b3;
            }
        }

        // ---- REPACK: cb2 staging -> B-frag capture (broadcast reads) ----
        {
            const float* c2b = stg2 + (r & 1) * 4096 + w * 256;
            const float v0 = c2b[0*32+kP], v1 = c2b[1*32+kP], v2 = c2b[2*32+kP],
                        v3 = c2b[3*32+kP], v4 = c2b[4*32+kP], v5 = c2b[5*32+kP],
                        v6 = c2b[6*32+kP], v7 = c2b[7*32+kP];
            const u16 e0 = f2bf_bits(v0), e1 = f2bf_bits(v1), e2 = f2bf_bits(v2),
                      e3 = f2bf_bits(v3), e4 = f2bf_bits(v4), e5 = f2bf_bits(v5),
                      e6 = f2bf_bits(v6), e7 = f2bf_bits(v7);
            const u16 f0 = f2bf_bits(v0 - bfbits2f(e0)), f1 = f2bf_bits(v1 - bfbits2f(e1)),
                      f2 = f2bf_bits(v2 - bfbits2f(e2)), f3 = f2bf_bits(v3 - bfbits2f(e3)),
                      f4 = f2bf_bits(v4 - bfbits2f(e4)), f5 = f2bf_bits(v5 - bfbits2f(e5)),
                      f6 = f2bf_bits(v6 - bfbits2f(e6)), f7 = f2bf_bits(v7 - bfbits2f(e7));
            if ((r & 1) == jh) {
                Bfh0 = (u32)e0 | ((u32)e1 << 16); Bfh1 = (u32)e2 | ((u32)e3 << 16);
                Bfh2 = (u32)e4 | ((u32)e5 << 16); Bfh3 = (u32)e6 | ((u32)e7 << 16);
                Bfl0 = (u32)f0 | ((u32)f1 << 16); Bfl1 = (u32)f2 | ((u32)f3 << 16);
                Bfl2 = (u32)f4 | ((u32)f5 << 16); Bfl3 = (u32)f6 | ((u32)f7 << 16);
            }
        }

        // ---- WINDOW at odd r: all-reg 32x32x16 MFMA (wave-private) ----
        if (r & 1) {
            U4Cast ua;
            ua.u[0]=Afh0; ua.u[1]=Afh1; ua.u[2]=Afh2; ua.u[3]=Afh3; const bf16x8 Ah = ua.v;
            ua.u[0]=Afl0; ua.u[1]=Afl1; ua.u[2]=Afl2; ua.u[3]=Afl3; const bf16x8 Al = ua.v;
            ua.u[0]=Bfh0; ua.u[1]=Bfh1; ua.u[2]=Bfh2; ua.u[3]=Bfh3; const bf16x8 Bh = ua.v;
            ua.u[0]=Bfl0; ua.u[1]=Bfl1; ua.u[2]=Bfl2; ua.u[3]=Bfl3; const bf16x8 Bl = ua.v;
            accw = __builtin_amdgcn_mfma_f32_32x32x16_bf16(Ah, Bh, accw, 0, 0, 0);
            accw = __builtin_amdgcn_mfma_f32_32x32x16_bf16(Ah, Bl, accw, 0, 0, 0);
            accw = __builtin_amdgcn_mfma_f32_32x32x16_bf16(Al, Bh, accw, 0, 0, 0);
        }
        __syncthreads();   // staging dbuf protection (one barrier per r)
    }
#undef LOADB
#undef BUILD

    // ---- epilogue: gelu + split -> gA frags (staging memory reused) ----
    {
#pragma unroll
        for (int rg = 0; rg < 16; rg++) {
            const int k = (rg & 3) + 8 * (rg >> 2) + 4 * jh;   // C/D row = out k-index
            const float v = gelu_exact(accw[rg]);
            const u16 hbits = f2bf_bits(v);
            const u16 lbits = f2bf_bits(v - bfbits2f(hbits));
            const int idx = (k * 64 + (kP >> 3) * 16 + w) * 8 + (kP & 7);
            gAh[idx] = hbits; gAl[idx] = lbits;
        }
    }
    __syncthreads();

    // ---- down-proj: y[16][256] = g @ W + b ; ALL 16 waves, wave w owns n-group w ----
    {
        f32x4 dacc = {0.f,0.f,0.f,0.f};
        const int wb = w * 16384 + l * 8;          // (ng*32+kc)*512 + l*8
#pragma unroll 2
        for (int kc = 0; kc < 32; kc++) {
            cu.f = *(const float4*)(gAh + (kc * 64 + l) * 8); const bf16x8 ah = cu.v;
            cu.f = *(const float4*)(gAl + (kc * 64 + l) * 8); const bf16x8 al = cu.v;
            ABCast c0, c1;
            c0.f = *(const float4*)(wfh + wb + kc * 512); const bf16x8 bh = c0.v;
            c1.f = *(const float4*)(wfl + wb + kc * 512); const bf16x8 bl = c1.v;
            dacc = __builtin_amdgcn_mfma_f32_16x16x32_bf16(ah, bh, dacc, 0, 0, 0);
            dacc = __builtin_amdgcn_mfma_f32_16x16x32_bf16(ah, bl, dacc, 0, 0, 0);
            dacc = __builtin_amdgcn_mfma_f32_16x16x32_bf16(al, bh, dacc, 0, 0, 0);
        }
        const int n0 = w * 16 + (l & 15);
        const float b0 = bias[n0];
        const int tb = t0 + 4 * (l >> 4);
#pragma unroll
        for (int rg = 0; rg < 4; rg++)
            y[(tb + rg) * 256 + n0] = dacc[rg] + b0;
    }
}

extern "C" void kernel_launch(void* const* d_in, const int* in_sizes, int n_in,
                              void* d_out, int out_size, void* d_ws, size_t ws_size,
                              hipStream_t stream)
{
    const float* x    = (const float*)d_in[0];
    const int*   nidx = (const int*)  d_in[1];
    const float* nw   = (const float*)d_in[2];
    const float* rec  = (const float*)d_in[3];
    const float* A1   = (const float*)d_in[4];
    const float* A2   = (const float*)d_in[5];
    const float* B1   = (const float*)d_in[6];
    const float* B2   = (const float*)d_in[7];
    const float* Wd   = (const float*)d_in[8];
    const float* bd   = (const float*)d_in[9];
    float* y  = (float*)d_out;

    float* wr  = (float*)d_ws;                   // 8192*32 f32
    float* h   = wr + 8192 * 32;                 // 8192*64 f32
    u16* wrAh  = (u16*)(h + 8192 * 64);          // 262144 u16
    u16* wrAl  = wrAh + 262144;
    u16* b1h   = wrAl + 262144;                  // 65536 u16 each
    u16* b1l   = b1h + 65536;
    u16* b2h   = b1l + 65536;
    u16* b2l   = b2h + 65536;
    u16* wfh   = b2l + 65536;                    // 262144 u16 each
    u16* wfl   = wfh + 262144;

    k_route <<<128,  64,   0, stream>>>(nidx, nw, rec, wr, wrAh, wrAl);
    k_prep  <<<192,  256,  0, stream>>>(B1, B2, b1h, b1l, b2h, b2l, Wd, wfh, wfl);
    k_stageA<<<1024, 512,  0, stream>>>(x, wr, A1, A2, h);
    k_fusedB<<<512,  1024, 0, stream>>>(h, wrAh, wrAl, b1h, b1l, b2h, b2l, wfh, wfl, bd, y);
}

// Round 17
// 96.933 us; speedup vs baseline: 2.3361x; 2.3361x over previous
//
#include <hip/hip_runtime.h>
#include <math.h>

// B*S = 8192 tokens, K=8, N_BASIS=32, RANK=8, D_MODEL=256, D_HID=1024
// ws: wr f32 | h f32 | wrAh/wrAl | bf1h,bf1l,bf2h,bf2l | wfh,wfl  (~5.8 MB)
// CHAMPION CONFIG (r12/r14 ~98us): original stageA (spill-free, latency-tolerant;
// two vectorization attempts failed: r15 32-way bank conflict, r16 VGPR spill —
// do not touch without -Rpass-analysis), fusedB v4 (~65us), merged k_prep,
// all-16-wave down-proj tail (both verified neutral in r15).

typedef unsigned short u16;
typedef unsigned int u32;
typedef __attribute__((ext_vector_type(8))) __bf16 bf16x8;
typedef __attribute__((ext_vector_type(4))) float f32x4;
typedef __attribute__((ext_vector_type(16))) float f32x16;
union ABCast { float4 f; bf16x8 v; };
union U4Cast { u32 u[4]; bf16x8 v; };
union BFBits { __bf16 b; u16 u; };
union Pack8 { u16 u[8]; float4 f; };

__device__ __forceinline__ float gelu_exact(float v) {
    return 0.5f * v * (1.0f + erff(v * 0.70710678118654752440f));
}
__device__ __forceinline__ u16 f2bf_bits(float f) { BFBits c; c.b = (__bf16)f; return c.u; }
__device__ __forceinline__ float bfbits2f(u16 u) { BFBits c; c.u = u; return (float)c.b; }

// ---------------- K1: routing -> wr f32 + wr A-frags (bf16 h/l) ----------------
__global__ __launch_bounds__(64) void k_route(
    const int* __restrict__ nidx, const float* __restrict__ nw,
    const float* __restrict__ recipes, float* __restrict__ wr_out,
    u16* __restrict__ wrAh, u16* __restrict__ wrAl)
{
    const int t = blockIdx.x * 64 + threadIdx.x;
    float acc[32];
#pragma unroll
    for (int n = 0; n < 32; n++) acc[n] = 0.f;
#pragma unroll
    for (int k = 0; k < 8; k++) {
        const int   id = nidx[t * 8 + k];
        const float wk = nw[t * 8 + k];
        const float4* row = (const float4*)(recipes + id * 32);
        float v[32];
#pragma unroll
        for (int q = 0; q < 8; q++) {
            float4 f = row[q];
            v[q*4+0] = f.x; v[q*4+1] = f.y; v[q*4+2] = f.z; v[q*4+3] = f.w;
        }
        float m = v[0];
#pragma unroll
        for (int n = 1; n < 32; n++) m = fmaxf(m, v[n]);
        float s = 0.f;
#pragma unroll
        for (int n = 0; n < 32; n++) { float e = expf(v[n] - m); v[n] = e; s += e; }
        const float iv = wk / s;
#pragma unroll
        for (int n = 0; n < 32; n++) acc[n] += v[n] * iv;
    }
    float4* o = (float4*)(wr_out + t * 32);
#pragma unroll
    for (int q = 0; q < 8; q++)
        o[q] = make_float4(acc[q*4+0], acc[q*4+1], acc[q*4+2], acc[q*4+3]);

    const int tg16 = t >> 4, tl = t & 15;
#pragma unroll
    for (int c = 0; c < 4; c++) {
        Pack8 ph, pl;
#pragma unroll
        for (int e = 0; e < 8; e++) {
            const float v = acc[c*8 + e];
            const u16 hb = f2bf_bits(v);
            ph.u[e] = hb;
            pl.u[e] = f2bf_bits(v - bfbits2f(hb));
        }
        const int lane = c * 16 + tl;
        *(float4*)(wrAh + (tg16*64 + lane)*8) = ph.f;
        *(float4*)(wrAl + (tg16*64 + lane)*8) = pl.f;
    }
}

// ---------------- K2: stage A  x[256] -> h[64], 8 tokens/block (ORIGINAL) --------
__global__ __launch_bounds__(512) void k_stageA(
    const float* __restrict__ x, const float* __restrict__ wr,
    const float* __restrict__ A1, const float* __restrict__ A2,
    float* __restrict__ h_out)
{
    __shared__ float ca[8 * 1024];
    __shared__ float tl[8 * 1088];
    const int tid = threadIdx.x;
    const int t0  = blockIdx.x * 8;
    {
        const int e2 = tid * 2;
        float2 c[8];
#pragma unroll
        for (int tt = 0; tt < 8; tt++) c[tt] = make_float2(0.f, 0.f);
#pragma unroll 4
        for (int n = 0; n < 32; n++) {
            const float2 a = *(const float2*)(A1 + n * 1024 + e2);
#pragma unroll
            for (int tt = 0; tt < 8; tt++) {
                const float s = wr[(t0 + tt) * 32 + n];
                c[tt].x += s * a.x; c[tt].y += s * a.y;
            }
        }
#pragma unroll
        for (int tt = 0; tt < 8; tt++) *(float2*)(ca + tt * 1024 + e2) = c[tt];
    }
    __syncthreads();
    {
        const int t = tid >> 6, g = tid & 63, j = g >> 2, eh = g & 3;
        float xr[16];
#pragma unroll
        for (int i = 0; i < 16; i++) xr[i] = x[(t0 + t) * 256 + i * 16 + j];
        float tr[16];
#pragma unroll
        for (int q = 0; q < 16; q++) tr[q] = 0.f;
#pragma unroll
        for (int i = 0; i < 16; i++) {
            const float xv = xr[i];
#pragma unroll
            for (int q = 0; q < 4; q++) {
                const float4 cv = *(const float4*)(ca + t * 1024 + i * 64 + eh * 16 + q * 4);
                tr[q*4+0] += xv * cv.x; tr[q*4+1] += xv * cv.y;
                tr[q*4+2] += xv * cv.z; tr[q*4+3] += xv * cv.w;
            }
        }
#pragma unroll
        for (int q = 0; q < 4; q++)
            *(float4*)(tl + t * 1088 + j * 68 + eh * 16 + q * 4) =
                make_float4(tr[q*4+0], tr[q*4+1], tr[q*4+2], tr[q*4+3]);
    }
    __syncthreads();
    {
        const int e2 = tid * 2;
        float2 c[8];
#pragma unroll
        for (int tt = 0; tt < 8; tt++) c[tt] = make_float2(0.f, 0.f);
#pragma unroll 4
        for (int n = 0; n < 32; n++) {
            const float2 a = *(const float2*)(A2 + n * 1024 + e2);
#pragma unroll
            for (int tt = 0; tt < 8; tt++) {
                const float s = wr[(t0 + tt) * 32 + n];
                c[tt].x += s * a.x; c[tt].y += s * a.y;
            }
        }
#pragma unroll
        for (int tt = 0; tt < 8; tt++) *(float2*)(ca + tt * 1024 + e2) = c[tt];
    }
    __syncthreads();
    {
        const int t = tid >> 6, g = tid & 63, k = g >> 3, l = g & 7;
        float acc = 0.f;
#pragma unroll
        for (int j = 0; j < 16; j++) {
#pragma unroll
            for (int r = 0; r < 8; r++) {
                acc += tl[t * 1088 + j * 68 + r * 8 + k] *
                       ca[t * 1024 + r * 128 + j * 8 + l];
            }
        }
        h_out[(t0 + t) * 64 + g] = acc;
    }
}

// ---------------- K3: prep (bsplit + wsplit merged) ----------------
__global__ __launch_bounds__(256) void k_prep(
    const float* __restrict__ B1, const float* __restrict__ B2,
    u16* __restrict__ o1h, u16* __restrict__ o1l,
    u16* __restrict__ o2h, u16* __restrict__ o2l,
    const float* __restrict__ W, u16* __restrict__ wfh, u16* __restrict__ wfl)
{
    if (blockIdx.x < 64) {
        const int slot = blockIdx.x * 256 + threadIdx.x;   // 0..16383
        const int bank = slot >> 13, r = (slot >> 10) & 7, g = (slot >> 6) & 15, l = slot & 63;
        const int c = l & 15, nb = 8 * (l >> 4);
        const int base = (bank == 0)
            ? ((g >> 1) * 256 + r * 32 + (g & 1) * 16 + c)
            : (r * 256 + (g >> 1) * 32 + (g & 1) * 16 + c);
        const float* S = (bank ? B2 : B1) + base + nb * 2048;
        Pack8 ph, pl;
#pragma unroll
        for (int e = 0; e < 8; e++) {
            const float v = S[e * 2048];
            const u16 hb = f2bf_bits(v);
            ph.u[e] = hb;
            pl.u[e] = f2bf_bits(v - bfbits2f(hb));
        }
        const int d = ((r * 16 + g) * 64 + l) * 8;
        *(float4*)((bank ? o2h : o1h) + d) = ph.f;
        *(float4*)((bank ? o2l : o1l) + d) = pl.f;
    } else {
        const int slot = (blockIdx.x - 64) * 256 + threadIdx.x;   // 0..32767
        const int ng = slot >> 11, kc = (slot >> 6) & 31, l = slot & 63;
        const float* S = W + (kc * 32 + 8 * (l >> 4)) * 256 + ng * 16 + (l & 15);
        Pack8 ph, pl;
#pragma unroll
        for (int e = 0; e < 8; e++) {
            const float v = S[e * 256];
            const u16 hb = f2bf_bits(v);
            ph.u[e] = hb;
            pl.u[e] = f2bf_bits(v - bfbits2f(hb));
        }
        const int d = ((ng * 32 + kc) * 64 + l) * 8;
        *(float4*)(wfh + d) = ph.f;
        *(float4*)(wfl + d) = pl.f;
    }
}

// ---------------- K4: fused stageB + down-proj v4 (all-16-wave down-proj) -------
__global__ __launch_bounds__(1024, 2) void k_fusedB(
    const float* __restrict__ hin,
    const u16* __restrict__ wrAh, const u16* __restrict__ wrAl,
    const u16* __restrict__ bf1h, const u16* __restrict__ bf1l,
    const u16* __restrict__ bf2h, const u16* __restrict__ bf2l,
    const u16* __restrict__ wfh, const u16* __restrict__ wfl,
    const float* __restrict__ bias, float* __restrict__ y)
{
    __shared__ __align__(16) unsigned char smem[65536];
    float* stg1 = (float*)smem;            // [2][16][256] f32 = 32KB (cb1 dbuf)
    float* stg2 = stg1 + 8192;             // [2][16][256] f32 = 32KB (cb2 dbuf)
    u16* gAh = (u16*)smem;                 // [32][64][8] u16 (phase-2 reuse, 32KB)
    u16* gAl = gAh + 16384;                // (32KB..64KB)

    const int tid = threadIdx.x;
    const int l   = tid & 63;
    const int w   = tid >> 6;              // 0..15 = token
    const int tg  = blockIdx.x;            // 16-token group (grid 512)
    const int t0  = tg * 16;
    const int kP  = l & 31;                // out-k row (A) / out-l col (B,C)
    const int jh  = l >> 5;

    // h for this wave's token (quad-j per lane; r-invariant)
    float hreg[32];
#pragma unroll
    for (int i = 0; i < 8; i++)
#pragma unroll
        for (int jj = 0; jj < 4; jj++)
            hreg[i*4+jj] = hin[(t0 + w) * 64 + i * 8 + jh * 4 + jj];

    // wr A-frags (16-token group)
    ABCast cu;
    cu.f = *(const float4*)(wrAh + (tg * 64 + l) * 8); const bf16x8 wra_h = cu.v;
    cu.f = *(const float4*)(wrAl + (tg * 64 + l) * 8); const bf16x8 wra_l = cu.v;

    // BUILD role: waves 0-7 -> cb1 staging, 8-15 -> cb2 staging; 2 groups each
    const bool isB2 = (w >= 8);
    const u16* bsrc_h = isB2 ? bf2h : bf1h;
    const u16* bsrc_l = isB2 ? bf2l : bf1l;
    float* cstg = isB2 ? stg2 : stg1;
    const int g0 = (w & 7) * 2;

    f32x16 accw = {0.f,0.f,0.f,0.f,0.f,0.f,0.f,0.f,0.f,0.f,0.f,0.f,0.f,0.f,0.f,0.f};
    u32 Afh0=0,Afh1=0,Afh2=0,Afh3=0, Afl0=0,Afl1=0,Afl2=0,Afl3=0;
    u32 Bfh0=0,Bfh1=0,Bfh2=0,Bfh3=0, Bfl0=0,Bfl1=0,Bfl2=0,Bfl3=0;

    float4 pbh0, pbl0, pbh1, pbl1;
#define LOADB(R) { const int rb_=(R)*16;                                        \
    pbh0 = *(const float4*)(bsrc_h + ((rb_+g0+0)*64+l)*8);                      \
    pbl0 = *(const float4*)(bsrc_l + ((rb_+g0+0)*64+l)*8);                      \
    pbh1 = *(const float4*)(bsrc_h + ((rb_+g0+1)*64+l)*8);                      \
    pbl1 = *(const float4*)(bsrc_l + ((rb_+g0+1)*64+l)*8); }
#define BUILD(BSEL) {                                                           \
    ABCast ch_, cl_;                                                            \
    __builtin_amdgcn_s_setprio(1);                                              \
    ch_.f = pbh0; cl_.f = pbl0;                                                 \
    f32x4 cc = {0.f,0.f,0.f,0.f};                                               \
    cc = __builtin_amdgcn_mfma_f32_16x16x32_bf16(wra_h, ch_.v, cc, 0, 0, 0);    \
    cc = __builtin_amdgcn_mfma_f32_16x16x32_bf16(wra_h, cl_.v, cc, 0, 0, 0);    \
    cc = __builtin_amdgcn_mfma_f32_16x16x32_bf16(wra_l, ch_.v, cc, 0, 0, 0);    \
    ch_.f = pbh1; cl_.f = pbl1;                                                 \
    f32x4 cc2 = {0.f,0.f,0.f,0.f};                                              \
    cc2 = __builtin_amdgcn_mfma_f32_16x16x32_bf16(wra_h, ch_.v, cc2, 0, 0, 0);  \
    cc2 = __builtin_amdgcn_mfma_f32_16x16x32_bf16(wra_h, cl_.v, cc2, 0, 0, 0);  \
    cc2 = __builtin_amdgcn_mfma_f32_16x16x32_bf16(wra_l, ch_.v, cc2, 0, 0, 0);  \
    __builtin_amdgcn_s_setprio(0);                                              \
    { const int gg = g0;                                                        \
      float* cd = cstg + (BSEL)*4096 + (gg>>1)*32 + (gg&1)*16 + (l&15);         \
      _Pragma("unroll")                                                         \
      for (int rg = 0; rg < 4; rg++) cd[(4*(l>>4)+rg)*256] = cc[rg]; }          \
    { const int gg = g0 + 1;                                                    \
      float* cd = cstg + (BSEL)*4096 + (gg>>1)*32 + (gg&1)*16 + (l&15);         \
      _Pragma("unroll")                                                         \
      for (int rg = 0; rg < 4; rg++) cd[(4*(l>>4)+rg)*256] = cc2[rg]; } }

    // prologue: build r=0 into buf0, prefetch r=1
    LOADB(0);
    BUILD(0);
    LOADB(1);
    __syncthreads();

#pragma unroll 1
    for (int r = 0; r < 8; r++) {
        if (r < 7) {
            BUILD((r+1)&1);
            if (r < 6) LOADB(r+2);
        }

        // ---- P2: quad-j t2 in regs -> pack -> shfl swap -> A-frag capture ----
        {
            const float* c1b = stg1 + (r & 1) * 4096 + w * 256;
            float t0q=0.f, t1q=0.f, t2q=0.f, t3q=0.f;
#pragma unroll
            for (int i = 0; i < 8; i++) {
                const float cv = c1b[i * 32 + kP];
                t0q += hreg[i*4+0] * cv; t1q += hreg[i*4+1] * cv;
                t2q += hreg[i*4+2] * cv; t3q += hreg[i*4+3] * cv;
            }
            const u16 h0 = f2bf_bits(t0q), h1 = f2bf_bits(t1q),
                      h2 = f2bf_bits(t2q), h3 = f2bf_bits(t3q);
            const u16 q0 = f2bf_bits(t0q - bfbits2f(h0)), q1 = f2bf_bits(t1q - bfbits2f(h1)),
                      q2 = f2bf_bits(t2q - bfbits2f(h2)), q3 = f2bf_bits(t3q - bfbits2f(h3));
            const u32 th0 = (u32)h0 | ((u32)h1 << 16), th1 = (u32)h2 | ((u32)h3 << 16);
            const u32 tl0 = (u32)q0 | ((u32)q1 << 16), tl1 = (u32)q2 | ((u32)q3 << 16);
            const u32 ph0 = (u32)__shfl_xor((int)th0, 32);
            const u32 ph1 = (u32)__shfl_xor((int)th1, 32);
            const u32 pl0 = (u32)__shfl_xor((int)tl0, 32);
            const u32 pl1 = (u32)__shfl_xor((int)tl1, 32);
            const u32 a0 = jh ? ph0 : th0, a1 = jh ? ph1 : th1;
            const u32 a2 = jh ? th0 : ph0, a3 = jh ? th1 : ph1;
            const u32 b0 = jh ? pl0 : tl0, b1 = jh ? pl1 : tl1;
            const u32 b2 = jh ? tl0 : pl0, b3 = jh ? tl1 : pl1;
            if ((r & 1) == jh) {
                Afh0 = a0; Afh1 = a1; Afh2 = a2; Afh3 = a3;
                Afl0 = b0; Afl1 = b1; Afl2 = b2; Afl3 = b3;
            }
        }

        // ---- REPACK: cb2 staging -> B-frag capture (broadcast reads) ----
        {
            const float* c2b = stg2 + (r & 1) * 4096 + w * 256;
            const float v0 = c2b[0*32+kP], v1 = c2b[1*32+kP], v2 = c2b[2*32+kP],
                        v3 = c2b[3*32+kP], v4 = c2b[4*32+kP], v5 = c2b[5*32+kP],
                        v6 = c2b[6*32+kP], v7 = c2b[7*32+kP];
            const u16 e0 = f2bf_bits(v0), e1 = f2bf_bits(v1), e2 = f2bf_bits(v2),
                      e3 = f2bf_bits(v3), e4 = f2bf_bits(v4), e5 = f2bf_bits(v5),
                      e6 = f2bf_bits(v6), e7 = f2bf_bits(v7);
            const u16 f0 = f2bf_bits(v0 - bfbits2f(e0)), f1 = f2bf_bits(v1 - bfbits2f(e1)),
                      f2 = f2bf_bits(v2 - bfbits2f(e2)), f3 = f2bf_bits(v3 - bfbits2f(e3)),
                      f4 = f2bf_bits(v4 - bfbits2f(e4)), f5 = f2bf_bits(v5 - bfbits2f(e5)),
                      f6 = f2bf_bits(v6 - bfbits2f(e6)), f7 = f2bf_bits(v7 - bfbits2f(e7));
            if ((r & 1) == jh) {
                Bfh0 = (u32)e0 | ((u32)e1 << 16); Bfh1 = (u32)e2 | ((u32)e3 << 16);
                Bfh2 = (u32)e4 | ((u32)e5 << 16); Bfh3 = (u32)e6 | ((u32)e7 << 16);
                Bfl0 = (u32)f0 | ((u32)f1 << 16); Bfl1 = (u32)f2 | ((u32)f3 << 16);
                Bfl2 = (u32)f4 | ((u32)f5 << 16); Bfl3 = (u32)f6 | ((u32)f7 << 16);
            }
        }

        // ---- WINDOW at odd r: all-reg 32x32x16 MFMA (wave-private) ----
        if (r & 1) {
            U4Cast ua;
            ua.u[0]=Afh0; ua.u[1]=Afh1; ua.u[2]=Afh2; ua.u[3]=Afh3; const bf16x8 Ah = ua.v;
            ua.u[0]=Afl0; ua.u[1]=Afl1; ua.u[2]=Afl2; ua.u[3]=Afl3; const bf16x8 Al = ua.v;
            ua.u[0]=Bfh0; ua.u[1]=Bfh1; ua.u[2]=Bfh2; ua.u[3]=Bfh3; const bf16x8 Bh = ua.v;
            ua.u[0]=Bfl0; ua.u[1]=Bfl1; ua.u[2]=Bfl2; ua.u[3]=Bfl3; const bf16x8 Bl = ua.v;
            accw = __builtin_amdgcn_mfma_f32_32x32x16_bf16(Ah, Bh, accw, 0, 0, 0);
            accw = __builtin_amdgcn_mfma_f32_32x32x16_bf16(Ah, Bl, accw, 0, 0, 0);
            accw = __builtin_amdgcn_mfma_f32_32x32x16_bf16(Al, Bh, accw, 0, 0, 0);
        }
        __syncthreads();   // staging dbuf protection (one barrier per r)
    }
#undef LOADB
#undef BUILD

    // ---- epilogue: gelu + split -> gA frags (staging memory reused) ----
    {
#pragma unroll
        for (int rg = 0; rg < 16; rg++) {
            const int k = (rg & 3) + 8 * (rg >> 2) + 4 * jh;   // C/D row = out k-index
            const float v = gelu_exact(accw[rg]);
            const u16 hbits = f2bf_bits(v);
            const u16 lbits = f2bf_bits(v - bfbits2f(hbits));
            const int idx = (k * 64 + (kP >> 3) * 16 + w) * 8 + (kP & 7);
            gAh[idx] = hbits; gAl[idx] = lbits;
        }
    }
    __syncthreads();

    // ---- down-proj: y[16][256] = g @ W + b ; ALL 16 waves, wave w owns n-group w ----
    {
        f32x4 dacc = {0.f,0.f,0.f,0.f};
        const int wb = w * 16384 + l * 8;          // (ng*32+kc)*512 + l*8
#pragma unroll 2
        for (int kc = 0; kc < 32; kc++) {
            cu.f = *(const float4*)(gAh + (kc * 64 + l) * 8); const bf16x8 ah = cu.v;
            cu.f = *(const float4*)(gAl + (kc * 64 + l) * 8); const bf16x8 al = cu.v;
            ABCast c0, c1;
            c0.f = *(const float4*)(wfh + wb + kc * 512); const bf16x8 bh = c0.v;
            c1.f = *(const float4*)(wfl + wb + kc * 512); const bf16x8 bl = c1.v;
            dacc = __builtin_amdgcn_mfma_f32_16x16x32_bf16(ah, bh, dacc, 0, 0, 0);
            dacc = __builtin_amdgcn_mfma_f32_16x16x32_bf16(ah, bl, dacc, 0, 0, 0);
            dacc = __builtin_amdgcn_mfma_f32_16x16x32_bf16(al, bh, dacc, 0, 0, 0);
        }
        const int n0 = w * 16 + (l & 15);
        const float b0 = bias[n0];
        const int tb = t0 + 4 * (l >> 4);
#pragma unroll
        for (int rg = 0; rg < 4; rg++)
            y[(tb + rg) * 256 + n0] = dacc[rg] + b0;
    }
}

extern "C" void kernel_launch(void* const* d_in, const int* in_sizes, int n_in,
                              void* d_out, int out_size, void* d_ws, size_t ws_size,
                              hipStream_t stream)
{
    const float* x    = (const float*)d_in[0];
    const int*   nidx = (const int*)  d_in[1];
    const float* nw   = (const float*)d_in[2];
    const float* rec  = (const float*)d_in[3];
    const float* A1   = (const float*)d_in[4];
    const float* A2   = (const float*)d_in[5];
    const float* B1   = (const float*)d_in[6];
    const float* B2   = (const float*)d_in[7];
    const float* Wd   = (const float*)d_in[8];
    const float* bd   = (const float*)d_in[9];
    float* y  = (float*)d_out;

    float* wr  = (float*)d_ws;                   // 8192*32 f32
    float* h   = wr + 8192 * 32;                 // 8192*64 f32
    u16* wrAh  = (u16*)(h + 8192 * 64);          // 262144 u16
    u16* wrAl  = wrAh + 262144;
    u16* b1h   = wrAl + 262144;                  // 65536 u16 each
    u16* b1l   = b1h + 65536;
    u16* b2h   = b1l + 65536;
    u16* b2l   = b2h + 65536;
    u16* wfh   = b2l + 65536;                    // 262144 u16 each
    u16* wfl   = wfh + 262144;

    k_route <<<128,  64,   0, stream>>>(nidx, nw, rec, wr, wrAh, wrAl);
    k_prep  <<<192,  256,  0, stream>>>(B1, B2, b1h, b1l, b2h, b2l, Wd, wfh, wfl);
    k_stageA<<<1024, 512,  0, stream>>>(x, wr, A1, A2, h);
    k_fusedB<<<512,  1024, 0, stream>>>(h, wrAh, wrAl, b1h, b1l, b2h, b2l, wfh, wfl, bd, y);
}

// Round 18
// 96.857 us; speedup vs baseline: 2.3379x; 1.0008x over previous
//
#include <hip/hip_runtime.h>
#include <math.h>

// B*S = 8192 tokens, K=8, N_BASIS=32, RANK=8, D_MODEL=256, D_HID=1024
// ws: wr f32 | h f32 | wrAh/wrAl | bf1h,bf1l,bf2h,bf2l | wfh,wfl  (~5.8 MB)
// CHAMPION (96.9us) + one isolated change: fusedB staging token-stride 256 -> 258
// (BUILD stores were 4-way bank-conflicted: stride 256 f32 ≡ 0 mod 32 banks;
//  258 spreads token-quads 8 banks apart -> 2-way = free; reads stay broadcast).
// stageA: ORIGINAL (two vectorization attempts failed: r15 banks, r16 spill).

typedef unsigned short u16;
typedef unsigned int u32;
typedef __attribute__((ext_vector_type(8))) __bf16 bf16x8;
typedef __attribute__((ext_vector_type(4))) float f32x4;
typedef __attribute__((ext_vector_type(16))) float f32x16;
union ABCast { float4 f; bf16x8 v; };
union U4Cast { u32 u[4]; bf16x8 v; };
union BFBits { __bf16 b; u16 u; };
union Pack8 { u16 u[8]; float4 f; };

__device__ __forceinline__ float gelu_exact(float v) {
    return 0.5f * v * (1.0f + erff(v * 0.70710678118654752440f));
}
__device__ __forceinline__ u16 f2bf_bits(float f) { BFBits c; c.b = (__bf16)f; return c.u; }
__device__ __forceinline__ float bfbits2f(u16 u) { BFBits c; c.u = u; return (float)c.b; }

// ---------------- K1: routing -> wr f32 + wr A-frags (bf16 h/l) ----------------
__global__ __launch_bounds__(64) void k_route(
    const int* __restrict__ nidx, const float* __restrict__ nw,
    const float* __restrict__ recipes, float* __restrict__ wr_out,
    u16* __restrict__ wrAh, u16* __restrict__ wrAl)
{
    const int t = blockIdx.x * 64 + threadIdx.x;
    float acc[32];
#pragma unroll
    for (int n = 0; n < 32; n++) acc[n] = 0.f;
#pragma unroll
    for (int k = 0; k < 8; k++) {
        const int   id = nidx[t * 8 + k];
        const float wk = nw[t * 8 + k];
        const float4* row = (const float4*)(recipes + id * 32);
        float v[32];
#pragma unroll
        for (int q = 0; q < 8; q++) {
            float4 f = row[q];
            v[q*4+0] = f.x; v[q*4+1] = f.y; v[q*4+2] = f.z; v[q*4+3] = f.w;
        }
        float m = v[0];
#pragma unroll
        for (int n = 1; n < 32; n++) m = fmaxf(m, v[n]);
        float s = 0.f;
#pragma unroll
        for (int n = 0; n < 32; n++) { float e = expf(v[n] - m); v[n] = e; s += e; }
        const float iv = wk / s;
#pragma unroll
        for (int n = 0; n < 32; n++) acc[n] += v[n] * iv;
    }
    float4* o = (float4*)(wr_out + t * 32);
#pragma unroll
    for (int q = 0; q < 8; q++)
        o[q] = make_float4(acc[q*4+0], acc[q*4+1], acc[q*4+2], acc[q*4+3]);

    const int tg16 = t >> 4, tl = t & 15;
#pragma unroll
    for (int c = 0; c < 4; c++) {
        Pack8 ph, pl;
#pragma unroll
        for (int e = 0; e < 8; e++) {
            const float v = acc[c*8 + e];
            const u16 hb = f2bf_bits(v);
            ph.u[e] = hb;
            pl.u[e] = f2bf_bits(v - bfbits2f(hb));
        }
        const int lane = c * 16 + tl;
        *(float4*)(wrAh + (tg16*64 + lane)*8) = ph.f;
        *(float4*)(wrAl + (tg16*64 + lane)*8) = pl.f;
    }
}

// ---------------- K2: stage A  x[256] -> h[64], 8 tokens/block (ORIGINAL) --------
__global__ __launch_bounds__(512) void k_stageA(
    const float* __restrict__ x, const float* __restrict__ wr,
    const float* __restrict__ A1, const float* __restrict__ A2,
    float* __restrict__ h_out)
{
    __shared__ float ca[8 * 1024];
    __shared__ float tl[8 * 1088];
    const int tid = threadIdx.x;
    const int t0  = blockIdx.x * 8;
    {
        const int e2 = tid * 2;
        float2 c[8];
#pragma unroll
        for (int tt = 0; tt < 8; tt++) c[tt] = make_float2(0.f, 0.f);
#pragma unroll 4
        for (int n = 0; n < 32; n++) {
            const float2 a = *(const float2*)(A1 + n * 1024 + e2);
#pragma unroll
            for (int tt = 0; tt < 8; tt++) {
                const float s = wr[(t0 + tt) * 32 + n];
                c[tt].x += s * a.x; c[tt].y += s * a.y;
            }
        }
#pragma unroll
        for (int tt = 0; tt < 8; tt++) *(float2*)(ca + tt * 1024 + e2) = c[tt];
    }
    __syncthreads();
    {
        const int t = tid >> 6, g = tid & 63, j = g >> 2, eh = g & 3;
        float xr[16];
#pragma unroll
        for (int i = 0; i < 16; i++) xr[i] = x[(t0 + t) * 256 + i * 16 + j];
        float tr[16];
#pragma unroll
        for (int q = 0; q < 16; q++) tr[q] = 0.f;
#pragma unroll
        for (int i = 0; i < 16; i++) {
            const float xv = xr[i];
#pragma unroll
            for (int q = 0; q < 4; q++) {
                const float4 cv = *(const float4*)(ca + t * 1024 + i * 64 + eh * 16 + q * 4);
                tr[q*4+0] += xv * cv.x; tr[q*4+1] += xv * cv.y;
                tr[q*4+2] += xv * cv.z; tr[q*4+3] += xv * cv.w;
            }
        }
#pragma unroll
        for (int q = 0; q < 4; q++)
            *(float4*)(tl + t * 1088 + j * 68 + eh * 16 + q * 4) =
                make_float4(tr[q*4+0], tr[q*4+1], tr[q*4+2], tr[q*4+3]);
    }
    __syncthreads();
    {
        const int e2 = tid * 2;
        float2 c[8];
#pragma unroll
        for (int tt = 0; tt < 8; tt++) c[tt] = make_float2(0.f, 0.f);
#pragma unroll 4
        for (int n = 0; n < 32; n++) {
            const float2 a = *(const float2*)(A2 + n * 1024 + e2);
#pragma unroll
            for (int tt = 0; tt < 8; tt++) {
                const float s = wr[(t0 + tt) * 32 + n];
                c[tt].x += s * a.x; c[tt].y += s * a.y;
            }
        }
#pragma unroll
        for (int tt = 0; tt < 8; tt++) *(float2*)(ca + tt * 1024 + e2) = c[tt];
    }
    __syncthreads();
    {
        const int t = tid >> 6, g = tid & 63, k = g >> 3, l = g & 7;
        float acc = 0.f;
#pragma unroll
        for (int j = 0; j < 16; j++) {
#pragma unroll
            for (int r = 0; r < 8; r++) {
                acc += tl[t * 1088 + j * 68 + r * 8 + k] *
                       ca[t * 1024 + r * 128 + j * 8 + l];
            }
        }
        h_out[(t0 + t) * 64 + g] = acc;
    }
}

// ---------------- K3: prep (bsplit + wsplit merged) ----------------
__global__ __launch_bounds__(256) void k_prep(
    const float* __restrict__ B1, const float* __restrict__ B2,
    u16* __restrict__ o1h, u16* __restrict__ o1l,
    u16* __restrict__ o2h, u16* __restrict__ o2l,
    const float* __restrict__ W, u16* __restrict__ wfh, u16* __restrict__ wfl)
{
    if (blockIdx.x < 64) {
        const int slot = blockIdx.x * 256 + threadIdx.x;   // 0..16383
        const int bank = slot >> 13, r = (slot >> 10) & 7, g = (slot >> 6) & 15, l = slot & 63;
        const int c = l & 15, nb = 8 * (l >> 4);
        const int base = (bank == 0)
            ? ((g >> 1) * 256 + r * 32 + (g & 1) * 16 + c)
            : (r * 256 + (g >> 1) * 32 + (g & 1) * 16 + c);
        const float* S = (bank ? B2 : B1) + base + nb * 2048;
        Pack8 ph, pl;
#pragma unroll
        for (int e = 0; e < 8; e++) {
            const float v = S[e * 2048];
            const u16 hb = f2bf_bits(v);
            ph.u[e] = hb;
            pl.u[e] = f2bf_bits(v - bfbits2f(hb));
        }
        const int d = ((r * 16 + g) * 64 + l) * 8;
        *(float4*)((bank ? o2h : o1h) + d) = ph.f;
        *(float4*)((bank ? o2l : o1l) + d) = pl.f;
    } else {
        const int slot = (blockIdx.x - 64) * 256 + threadIdx.x;   // 0..32767
        const int ng = slot >> 11, kc = (slot >> 6) & 31, l = slot & 63;
        const float* S = W + (kc * 32 + 8 * (l >> 4)) * 256 + ng * 16 + (l & 15);
        Pack8 ph, pl;
#pragma unroll
        for (int e = 0; e < 8; e++) {
            const float v = S[e * 256];
            const u16 hb = f2bf_bits(v);
            ph.u[e] = hb;
            pl.u[e] = f2bf_bits(v - bfbits2f(hb));
        }
        const int d = ((ng * 32 + kc) * 64 + l) * 8;
        *(float4*)(wfh + d) = ph.f;
        *(float4*)(wfl + d) = pl.f;
    }
}

// ---------------- K4: fused stageB + down-proj v4 (staging stride 258) ----------
__global__ __launch_bounds__(1024, 2) void k_fusedB(
    const float* __restrict__ hin,
    const u16* __restrict__ wrAh, const u16* __restrict__ wrAl,
    const u16* __restrict__ bf1h, const u16* __restrict__ bf1l,
    const u16* __restrict__ bf2h, const u16* __restrict__ bf2l,
    const u16* __restrict__ wfh, const u16* __restrict__ wfl,
    const float* __restrict__ bias, float* __restrict__ y)
{
    __shared__ __align__(16) unsigned char smem[66048];
    float* stg1 = (float*)smem;            // [2][16][258] f32 (cb1 dbuf, stride 258)
    float* stg2 = stg1 + 8256;             // [2][16][258] f32 (cb2 dbuf)
    u16* gAh = (u16*)smem;                 // [32][64][8] u16 (phase-2 reuse, 32KB)
    u16* gAl = gAh + 16384;                // (32KB..64KB)

    const int tid = threadIdx.x;
    const int l   = tid & 63;
    const int w   = tid >> 6;              // 0..15 = token
    const int tg  = blockIdx.x;            // 16-token group (grid 512)
    const int t0  = tg * 16;
    const int kP  = l & 31;                // out-k row (A) / out-l col (B,C)
    const int jh  = l >> 5;

    // h for this wave's token (quad-j per lane; r-invariant)
    float hreg[32];
#pragma unroll
    for (int i = 0; i < 8; i++)
#pragma unroll
        for (int jj = 0; jj < 4; jj++)
            hreg[i*4+jj] = hin[(t0 + w) * 64 + i * 8 + jh * 4 + jj];

    // wr A-frags (16-token group)
    ABCast cu;
    cu.f = *(const float4*)(wrAh + (tg * 64 + l) * 8); const bf16x8 wra_h = cu.v;
    cu.f = *(const float4*)(wrAl + (tg * 64 + l) * 8); const bf16x8 wra_l = cu.v;

    // BUILD role: waves 0-7 -> cb1 staging, 8-15 -> cb2 staging; 2 groups each
    const bool isB2 = (w >= 8);
    const u16* bsrc_h = isB2 ? bf2h : bf1h;
    const u16* bsrc_l = isB2 ? bf2l : bf1l;
    float* cstg = isB2 ? stg2 : stg1;
    const int g0 = (w & 7) * 2;

    f32x16 accw = {0.f,0.f,0.f,0.f,0.f,0.f,0.f,0.f,0.f,0.f,0.f,0.f,0.f,0.f,0.f,0.f};
    u32 Afh0=0,Afh1=0,Afh2=0,Afh3=0, Afl0=0,Afl1=0,Afl2=0,Afl3=0;
    u32 Bfh0=0,Bfh1=0,Bfh2=0,Bfh3=0, Bfl0=0,Bfl1=0,Bfl2=0,Bfl3=0;

    float4 pbh0, pbl0, pbh1, pbl1;
#define LOADB(R) { const int rb_=(R)*16;                                        \
    pbh0 = *(const float4*)(bsrc_h + ((rb_+g0+0)*64+l)*8);                      \
    pbl0 = *(const float4*)(bsrc_l + ((rb_+g0+0)*64+l)*8);                      \
    pbh1 = *(const float4*)(bsrc_h + ((rb_+g0+1)*64+l)*8);                      \
    pbl1 = *(const float4*)(bsrc_l + ((rb_+g0+1)*64+l)*8); }
#define BUILD(BSEL) {                                                           \
    ABCast ch_, cl_;                                                            \
    __builtin_amdgcn_s_setprio(1);                                              \
    ch_.f = pbh0; cl_.f = pbl0;                                                 \
    f32x4 cc = {0.f,0.f,0.f,0.f};                                               \
    cc = __builtin_amdgcn_mfma_f32_16x16x32_bf16(wra_h, ch_.v, cc, 0, 0, 0);    \
    cc = __builtin_amdgcn_mfma_f32_16x16x32_bf16(wra_h, cl_.v, cc, 0, 0, 0);    \
    cc = __builtin_amdgcn_mfma_f32_16x16x32_bf16(wra_l, ch_.v, cc, 0, 0, 0);    \
    ch_.f = pbh1; cl_.f = pbl1;                                                 \
    f32x4 cc2 = {0.f,0.f,0.f,0.f};                                              \
    cc2 = __builtin_amdgcn_mfma_f32_16x16x32_bf16(wra_h, ch_.v, cc2, 0, 0, 0);  \
    cc2 = __builtin_amdgcn_mfma_f32_16x16x32_bf16(wra_h, cl_.v, cc2, 0, 0, 0);  \
    cc2 = __builtin_amdgcn_mfma_f32_16x16x32_bf16(wra_l, ch_.v, cc2, 0, 0, 0);  \
    __builtin_amdgcn_s_setprio(0);                                              \
    { const int gg = g0;                                                        \
      float* cd = cstg + (BSEL)*4128 + (gg>>1)*32 + (gg&1)*16 + (l&15);         \
      _Pragma("unroll")                                                         \
      for (int rg = 0; rg < 4; rg++) cd[(4*(l>>4)+rg)*258] = cc[rg]; }          \
    { const int gg = g0 + 1;                                                    \
      float* cd = cstg + (BSEL)*4128 + (gg>>1)*32 + (gg&1)*16 + (l&15);         \
      _Pragma("unroll")                                                         \
      for (int rg = 0; rg < 4; rg++) cd[(4*(l>>4)+rg)*258] = cc2[rg]; } }

    // prologue: build r=0 into buf0, prefetch r=1
    LOADB(0);
    BUILD(0);
    LOADB(1);
    __syncthreads();

#pragma unroll 1
    for (int r = 0; r < 8; r++) {
        if (r < 7) {
            BUILD((r+1)&1);
            if (r < 6) LOADB(r+2);
        }

        // ---- P2: quad-j t2 in regs -> pack -> shfl swap -> A-frag capture ----
        {
            const float* c1b = stg1 + (r & 1) * 4128 + w * 258;
            float t0q=0.f, t1q=0.f, t2q=0.f, t3q=0.f;
#pragma unroll
            for (int i = 0; i < 8; i++) {
                const float cv = c1b[i * 32 + kP];
                t0q += hreg[i*4+0] * cv; t1q += hreg[i*4+1] * cv;
                t2q += hreg[i*4+2] * cv; t3q += hreg[i*4+3] * cv;
            }
            const u16 h0 = f2bf_bits(t0q), h1 = f2bf_bits(t1q),
                      h2 = f2bf_bits(t2q), h3 = f2bf_bits(t3q);
            const u16 q0 = f2bf_bits(t0q - bfbits2f(h0)), q1 = f2bf_bits(t1q - bfbits2f(h1)),
                      q2 = f2bf_bits(t2q - bfbits2f(h2)), q3 = f2bf_bits(t3q - bfbits2f(h3));
            const u32 th0 = (u32)h0 | ((u32)h1 << 16), th1 = (u32)h2 | ((u32)h3 << 16);
            const u32 tl0 = (u32)q0 | ((u32)q1 << 16), tl1 = (u32)q2 | ((u32)q3 << 16);
            const u32 ph0 = (u32)__shfl_xor((int)th0, 32);
            const u32 ph1 = (u32)__shfl_xor((int)th1, 32);
            const u32 pl0 = (u32)__shfl_xor((int)tl0, 32);
            const u32 pl1 = (u32)__shfl_xor((int)tl1, 32);
            const u32 a0 = jh ? ph0 : th0, a1 = jh ? ph1 : th1;
            const u32 a2 = jh ? th0 : ph0, a3 = jh ? th1 : ph1;
            const u32 b0 = jh ? pl0 : tl0, b1 = jh ? pl1 : tl1;
            const u32 b2 = jh ? tl0 : pl0, b3 = jh ? tl1 : pl1;
            if ((r & 1) == jh) {
                Afh0 = a0; Afh1 = a1; Afh2 = a2; Afh3 = a3;
                Afl0 = b0; Afl1 = b1; Afl2 = b2; Afl3 = b3;
            }
        }

        // ---- REPACK: cb2 staging -> B-frag capture (broadcast reads) ----
        {
            const float* c2b = stg2 + (r & 1) * 4128 + w * 258;
            const float v0 = c2b[0*32+kP], v1 = c2b[1*32+kP], v2 = c2b[2*32+kP],
                        v3 = c2b[3*32+kP], v4 = c2b[4*32+kP], v5 = c2b[5*32+kP],
                        v6 = c2b[6*32+kP], v7 = c2b[7*32+kP];
            const u16 e0 = f2bf_bits(v0), e1 = f2bf_bits(v1), e2 = f2bf_bits(v2),
                      e3 = f2bf_bits(v3), e4 = f2bf_bits(v4), e5 = f2bf_bits(v5),
                      e6 = f2bf_bits(v6), e7 = f2bf_bits(v7);
            const u16 f0 = f2bf_bits(v0 - bfbits2f(e0)), f1 = f2bf_bits(v1 - bfbits2f(e1)),
                      f2 = f2bf_bits(v2 - bfbits2f(e2)), f3 = f2bf_bits(v3 - bfbits2f(e3)),
                      f4 = f2bf_bits(v4 - bfbits2f(e4)), f5 = f2bf_bits(v5 - bfbits2f(e5)),
                      f6 = f2bf_bits(v6 - bfbits2f(e6)), f7 = f2bf_bits(v7 - bfbits2f(e7));
            if ((r & 1) == jh) {
                Bfh0 = (u32)e0 | ((u32)e1 << 16); Bfh1 = (u32)e2 | ((u32)e3 << 16);
                Bfh2 = (u32)e4 | ((u32)e5 << 16); Bfh3 = (u32)e6 | ((u32)e7 << 16);
                Bfl0 = (u32)f0 | ((u32)f1 << 16); Bfl1 = (u32)f2 | ((u32)f3 << 16);
                Bfl2 = (u32)f4 | ((u32)f5 << 16); Bfl3 = (u32)f6 | ((u32)f7 << 16);
            }
        }

        // ---- WINDOW at odd r: all-reg 32x32x16 MFMA (wave-private) ----
        if (r & 1) {
            U4Cast ua;
            ua.u[0]=Afh0; ua.u[1]=Afh1; ua.u[2]=Afh2; ua.u[3]=Afh3; const bf16x8 Ah = ua.v;
            ua.u[0]=Afl0; ua.u[1]=Afl1; ua.u[2]=Afl2; ua.u[3]=Afl3; const bf16x8 Al = ua.v;
            ua.u[0]=Bfh0; ua.u[1]=Bfh1; ua.u[2]=Bfh2; ua.u[3]=Bfh3; const bf16x8 Bh = ua.v;
            ua.u[0]=Bfl0; ua.u[1]=Bfl1; ua.u[2]=Bfl2; ua.u[3]=Bfl3; const bf16x8 Bl = ua.v;
            accw = __builtin_amdgcn_mfma_f32_32x32x16_bf16(Ah, Bh, accw, 0, 0, 0);
            accw = __builtin_amdgcn_mfma_f32_32x32x16_bf16(Ah, Bl, accw, 0, 0, 0);
            accw = __builtin_amdgcn_mfma_f32_32x32x16_bf16(Al, Bh, accw, 0, 0, 0);
        }
        __syncthreads();   // staging dbuf protection (one barrier per r)
    }
#undef LOADB
#undef BUILD

    // ---- epilogue: gelu + split -> gA frags (staging memory reused) ----
    {
#pragma unroll
        for (int rg = 0; rg < 16; rg++) {
            const int k = (rg & 3) + 8 * (rg >> 2) + 4 * jh;   // C/D row = out k-index
            const float v = gelu_exact(accw[rg]);
            const u16 hbits = f2bf_bits(v);
            const u16 lbits = f2bf_bits(v - bfbits2f(hbits));
            const int idx = (k * 64 + (kP >> 3) * 16 + w) * 8 + (kP & 7);
            gAh[idx] = hbits; gAl[idx] = lbits;
        }
    }
    __syncthreads();

    // ---- down-proj: y[16][256] = g @ W + b ; ALL 16 waves, wave w owns n-group w ----
    {
        f32x4 dacc = {0.f,0.f,0.f,0.f};
        const int wb = w * 16384 + l * 8;          // (ng*32+kc)*512 + l*8
#pragma unroll 2
        for (int kc = 0; kc < 32; kc++) {
            cu.f = *(const float4*)(gAh + (kc * 64 + l) * 8); const bf16x8 ah = cu.v;
            cu.f = *(const float4*)(gAl + (kc * 64 + l) * 8); const bf16x8 al = cu.v;
            ABCast c0, c1;
            c0.f = *(const float4*)(wfh + wb + kc * 512); const bf16x8 bh = c0.v;
            c1.f = *(const float4*)(wfl + wb + kc * 512); const bf16x8 bl = c1.v;
            dacc = __builtin_amdgcn_mfma_f32_16x16x32_bf16(ah, bh, dacc, 0, 0, 0);
            dacc = __builtin_amdgcn_mfma_f32_16x16x32_bf16(ah, bl, dacc, 0, 0, 0);
            dacc = __builtin_amdgcn_mfma_f32_16x16x32_bf16(al, bh, dacc, 0, 0, 0);
        }
        const int n0 = w * 16 + (l & 15);
        const float b0 = bias[n0];
        const int tb = t0 + 4 * (l >> 4);
#pragma unroll
        for (int rg = 0; rg < 4; rg++)
            y[(tb + rg) * 256 + n0] = dacc[rg] + b0;
    }
}

extern "C" void kernel_launch(void* const* d_in, const int* in_sizes, int n_in,
                              void* d_out, int out_size, void* d_ws, size_t ws_size,
                              hipStream_t stream)
{
    const float* x    = (const float*)d_in[0];
    const int*   nidx = (const int*)  d_in[1];
    const float* nw   = (const float*)d_in[2];
    const float* rec  = (const float*)d_in[3];
    const float* A1   = (const float*)d_in[4];
    const float* A2   = (const float*)d_in[5];
    const float* B1   = (const float*)d_in[6];
    const float* B2   = (const float*)d_in[7];
    const float* Wd   = (const float*)d_in[8];
    const float* bd   = (const float*)d_in[9];
    float* y  = (float*)d_out;

    float* wr  = (float*)d_ws;                   // 8192*32 f32
    float* h   = wr + 8192 * 32;                 // 8192*64 f32
    u16* wrAh  = (u16*)(h + 8192 * 64);          // 262144 u16
    u16* wrAl  = wrAh + 262144;
    u16* b1h   = wrAl + 262144;                  // 65536 u16 each
    u16* b1l   = b1h + 65536;
    u16* b2h   = b1l + 65536;
    u16* b2l   = b2h + 65536;
    u16* wfh   = b2l + 65536;                    // 262144 u16 each
    u16* wfl   = wfh + 262144;

    k_route <<<128,  64,   0, stream>>>(nidx, nw, rec, wr, wrAh, wrAl);
    k_prep  <<<192,  256,  0, stream>>>(B1, B2, b1h, b1l, b2h, b2l, Wd, wfh, wfl);
    k_stageA<<<1024, 512,  0, stream>>>(x, wr, A1, A2, h);
    k_fusedB<<<512,  1024, 0, stream>>>(h, wrAh, wrAl, b1h, b1l, b2h, b2l, wfh, wfl, bd, y);
}

// Round 19
// 96.357 us; speedup vs baseline: 2.3501x; 1.0052x over previous
//
#include <hip/hip_runtime.h>
#include <math.h>

// B*S = 8192 tokens, K=8, N_BASIS=32, RANK=8, D_MODEL=256, D_HID=1024
// ws: wr f32 | h f32 | wrAh/wrAl | bf1h,bf1l,bf2h,bf2l | wfh,wfl  (~5.8 MB)
// CHAMPION (96.9us) + one isolated change: gA chunk swizzle g(c)=c^((c>>4)&3).
// r18 located the constant 2.62M bank conflicts in the EPILOGUE u16 stores
// (banks w*4+(e>>1): 8-way); swizzle spreads token-quads across 16 banks (2-way
// = free), read side applies the same involution (within-16-lane permutation ->
// still linear/conflict-free/16B-aligned).
// stageA: ORIGINAL (r15 banks / r16 spill — do not touch).

typedef unsigned short u16;
typedef unsigned int u32;
typedef __attribute__((ext_vector_type(8))) __bf16 bf16x8;
typedef __attribute__((ext_vector_type(4))) float f32x4;
typedef __attribute__((ext_vector_type(16))) float f32x16;
union ABCast { float4 f; bf16x8 v; };
union U4Cast { u32 u[4]; bf16x8 v; };
union BFBits { __bf16 b; u16 u; };
union Pack8 { u16 u[8]; float4 f; };

__device__ __forceinline__ float gelu_exact(float v) {
    return 0.5f * v * (1.0f + erff(v * 0.70710678118654752440f));
}
__device__ __forceinline__ u16 f2bf_bits(float f) { BFBits c; c.b = (__bf16)f; return c.u; }
__device__ __forceinline__ float bfbits2f(u16 u) { BFBits c; c.u = u; return (float)c.b; }

// ---------------- K1: routing -> wr f32 + wr A-frags (bf16 h/l) ----------------
__global__ __launch_bounds__(64) void k_route(
    const int* __restrict__ nidx, const float* __restrict__ nw,
    const float* __restrict__ recipes, float* __restrict__ wr_out,
    u16* __restrict__ wrAh, u16* __restrict__ wrAl)
{
    const int t = blockIdx.x * 64 + threadIdx.x;
    float acc[32];
#pragma unroll
    for (int n = 0; n < 32; n++) acc[n] = 0.f;
#pragma unroll
    for (int k = 0; k < 8; k++) {
        const int   id = nidx[t * 8 + k];
        const float wk = nw[t * 8 + k];
        const float4* row = (const float4*)(recipes + id * 32);
        float v[32];
#pragma unroll
        for (int q = 0; q < 8; q++) {
            float4 f = row[q];
            v[q*4+0] = f.x; v[q*4+1] = f.y; v[q*4+2] = f.z; v[q*4+3] = f.w;
        }
        float m = v[0];
#pragma unroll
        for (int n = 1; n < 32; n++) m = fmaxf(m, v[n]);
        float s = 0.f;
#pragma unroll
        for (int n = 0; n < 32; n++) { float e = expf(v[n] - m); v[n] = e; s += e; }
        const float iv = wk / s;
#pragma unroll
        for (int n = 0; n < 32; n++) acc[n] += v[n] * iv;
    }
    float4* o = (float4*)(wr_out + t * 32);
#pragma unroll
    for (int q = 0; q < 8; q++)
        o[q] = make_float4(acc[q*4+0], acc[q*4+1], acc[q*4+2], acc[q*4+3]);

    const int tg16 = t >> 4, tl = t & 15;
#pragma unroll
    for (int c = 0; c < 4; c++) {
        Pack8 ph, pl;
#pragma unroll
        for (int e = 0; e < 8; e++) {
            const float v = acc[c*8 + e];
            const u16 hb = f2bf_bits(v);
            ph.u[e] = hb;
            pl.u[e] = f2bf_bits(v - bfbits2f(hb));
        }
        const int lane = c * 16 + tl;
        *(float4*)(wrAh + (tg16*64 + lane)*8) = ph.f;
        *(float4*)(wrAl + (tg16*64 + lane)*8) = pl.f;
    }
}

// ---------------- K2: stage A  x[256] -> h[64], 8 tokens/block (ORIGINAL) --------
__global__ __launch_bounds__(512) void k_stageA(
    const float* __restrict__ x, const float* __restrict__ wr,
    const float* __restrict__ A1, const float* __restrict__ A2,
    float* __restrict__ h_out)
{
    __shared__ float ca[8 * 1024];
    __shared__ float tl[8 * 1088];
    const int tid = threadIdx.x;
    const int t0  = blockIdx.x * 8;
    {
        const int e2 = tid * 2;
        float2 c[8];
#pragma unroll
        for (int tt = 0; tt < 8; tt++) c[tt] = make_float2(0.f, 0.f);
#pragma unroll 4
        for (int n = 0; n < 32; n++) {
            const float2 a = *(const float2*)(A1 + n * 1024 + e2);
#pragma unroll
            for (int tt = 0; tt < 8; tt++) {
                const float s = wr[(t0 + tt) * 32 + n];
                c[tt].x += s * a.x; c[tt].y += s * a.y;
            }
        }
#pragma unroll
        for (int tt = 0; tt < 8; tt++) *(float2*)(ca + tt * 1024 + e2) = c[tt];
    }
    __syncthreads();
    {
        const int t = tid >> 6, g = tid & 63, j = g >> 2, eh = g & 3;
        float xr[16];
#pragma unroll
        for (int i = 0; i < 16; i++) xr[i] = x[(t0 + t) * 256 + i * 16 + j];
        float tr[16];
#pragma unroll
        for (int q = 0; q < 16; q++) tr[q] = 0.f;
#pragma unroll
        for (int i = 0; i < 16; i++) {
            const float xv = xr[i];
#pragma unroll
            for (int q = 0; q < 4; q++) {
                const float4 cv = *(const float4*)(ca + t * 1024 + i * 64 + eh * 16 + q * 4);
                tr[q*4+0] += xv * cv.x; tr[q*4+1] += xv * cv.y;
                tr[q*4+2] += xv * cv.z; tr[q*4+3] += xv * cv.w;
            }
        }
#pragma unroll
        for (int q = 0; q < 4; q++)
            *(float4*)(tl + t * 1088 + j * 68 + eh * 16 + q * 4) =
                make_float4(tr[q*4+0], tr[q*4+1], tr[q*4+2], tr[q*4+3]);
    }
    __syncthreads();
    {
        const int e2 = tid * 2;
        float2 c[8];
#pragma unroll
        for (int tt = 0; tt < 8; tt++) c[tt] = make_float2(0.f, 0.f);
#pragma unroll 4
        for (int n = 0; n < 32; n++) {
            const float2 a = *(const float2*)(A2 + n * 1024 + e2);
#pragma unroll
            for (int tt = 0; tt < 8; tt++) {
                const float s = wr[(t0 + tt) * 32 + n];
                c[tt].x += s * a.x; c[tt].y += s * a.y;
            }
        }
#pragma unroll
        for (int tt = 0; tt < 8; tt++) *(float2*)(ca + tt * 1024 + e2) = c[tt];
    }
    __syncthreads();
    {
        const int t = tid >> 6, g = tid & 63, k = g >> 3, l = g & 7;
        float acc = 0.f;
#pragma unroll
        for (int j = 0; j < 16; j++) {
#pragma unroll
            for (int r = 0; r < 8; r++) {
                acc += tl[t * 1088 + j * 68 + r * 8 + k] *
                       ca[t * 1024 + r * 128 + j * 8 + l];
            }
        }
        h_out[(t0 + t) * 64 + g] = acc;
    }
}

// ---------------- K3: prep (bsplit + wsplit merged) ----------------
__global__ __launch_bounds__(256) void k_prep(
    const float* __restrict__ B1, const float* __restrict__ B2,
    u16* __restrict__ o1h, u16* __restrict__ o1l,
    u16* __restrict__ o2h, u16* __restrict__ o2l,
    const float* __restrict__ W, u16* __restrict__ wfh, u16* __restrict__ wfl)
{
    if (blockIdx.x < 64) {
        const int slot = blockIdx.x * 256 + threadIdx.x;   // 0..16383
        const int bank = slot >> 13, r = (slot >> 10) & 7, g = (slot >> 6) & 15, l = slot & 63;
        const int c = l & 15, nb = 8 * (l >> 4);
        const int base = (bank == 0)
            ? ((g >> 1) * 256 + r * 32 + (g & 1) * 16 + c)
            : (r * 256 + (g >> 1) * 32 + (g & 1) * 16 + c);
        const float* S = (bank ? B2 : B1) + base + nb * 2048;
        Pack8 ph, pl;
#pragma unroll
        for (int e = 0; e < 8; e++) {
            const float v = S[e * 2048];
            const u16 hb = f2bf_bits(v);
            ph.u[e] = hb;
            pl.u[e] = f2bf_bits(v - bfbits2f(hb));
        }
        const int d = ((r * 16 + g) * 64 + l) * 8;
        *(float4*)((bank ? o2h : o1h) + d) = ph.f;
        *(float4*)((bank ? o2l : o1l) + d) = pl.f;
    } else {
        const int slot = (blockIdx.x - 64) * 256 + threadIdx.x;   // 0..32767
        const int ng = slot >> 11, kc = (slot >> 6) & 31, l = slot & 63;
        const float* S = W + (kc * 32 + 8 * (l >> 4)) * 256 + ng * 16 + (l & 15);
        Pack8 ph, pl;
#pragma unroll
        for (int e = 0; e < 8; e++) {
            const float v = S[e * 256];
            const u16 hb = f2bf_bits(v);
            ph.u[e] = hb;
            pl.u[e] = f2bf_bits(v - bfbits2f(hb));
        }
        const int d = ((ng * 32 + kc) * 64 + l) * 8;
        *(float4*)(wfh + d) = ph.f;
        *(float4*)(wfl + d) = pl.f;
    }
}

// ---------------- K4: fused stageB + down-proj v4 (gA chunk swizzle) ------------
__global__ __launch_bounds__(1024, 2) void k_fusedB(
    const float* __restrict__ hin,
    const u16* __restrict__ wrAh, const u16* __restrict__ wrAl,
    const u16* __restrict__ bf1h, const u16* __restrict__ bf1l,
    const u16* __restrict__ bf2h, const u16* __restrict__ bf2l,
    const u16* __restrict__ wfh, const u16* __restrict__ wfl,
    const float* __restrict__ bias, float* __restrict__ y)
{
    __shared__ __align__(16) unsigned char smem[66048];
    float* stg1 = (float*)smem;            // [2][16][258] f32 (cb1 dbuf, stride 258)
    float* stg2 = stg1 + 8256;             // [2][16][258] f32 (cb2 dbuf)
    u16* gAh = (u16*)smem;                 // [32][64][8] u16 (phase-2 reuse, 32KB)
    u16* gAl = gAh + 16384;                // (32KB..64KB)

    const int tid = threadIdx.x;
    const int l   = tid & 63;
    const int w   = tid >> 6;              // 0..15 = token
    const int tg  = blockIdx.x;            // 16-token group (grid 512)
    const int t0  = tg * 16;
    const int kP  = l & 31;                // out-k row (A) / out-l col (B,C)
    const int jh  = l >> 5;

    // h for this wave's token (quad-j per lane; r-invariant)
    float hreg[32];
#pragma unroll
    for (int i = 0; i < 8; i++)
#pragma unroll
        for (int jj = 0; jj < 4; jj++)
            hreg[i*4+jj] = hin[(t0 + w) * 64 + i * 8 + jh * 4 + jj];

    // wr A-frags (16-token group)
    ABCast cu;
    cu.f = *(const float4*)(wrAh + (tg * 64 + l) * 8); const bf16x8 wra_h = cu.v;
    cu.f = *(const float4*)(wrAl + (tg * 64 + l) * 8); const bf16x8 wra_l = cu.v;

    // BUILD role: waves 0-7 -> cb1 staging, 8-15 -> cb2 staging; 2 groups each
    const bool isB2 = (w >= 8);
    const u16* bsrc_h = isB2 ? bf2h : bf1h;
    const u16* bsrc_l = isB2 ? bf2l : bf1l;
    float* cstg = isB2 ? stg2 : stg1;
    const int g0 = (w & 7) * 2;

    f32x16 accw = {0.f,0.f,0.f,0.f,0.f,0.f,0.f,0.f,0.f,0.f,0.f,0.f,0.f,0.f,0.f,0.f};
    u32 Afh0=0,Afh1=0,Afh2=0,Afh3=0, Afl0=0,Afl1=0,Afl2=0,Afl3=0;
    u32 Bfh0=0,Bfh1=0,Bfh2=0,Bfh3=0, Bfl0=0,Bfl1=0,Bfl2=0,Bfl3=0;

    float4 pbh0, pbl0, pbh1, pbl1;
#define LOADB(R) { const int rb_=(R)*16;                                        \
    pbh0 = *(const float4*)(bsrc_h + ((rb_+g0+0)*64+l)*8);                      \
    pbl0 = *(const float4*)(bsrc_l + ((rb_+g0+0)*64+l)*8);                      \
    pbh1 = *(const float4*)(bsrc_h + ((rb_+g0+1)*64+l)*8);                      \
    pbl1 = *(const float4*)(bsrc_l + ((rb_+g0+1)*64+l)*8); }
#define BUILD(BSEL) {                                                           \
    ABCast ch_, cl_;                                                            \
    __builtin_amdgcn_s_setprio(1);                                              \
    ch_.f = pbh0; cl_.f = pbl0;                                                 \
    f32x4 cc = {0.f,0.f,0.f,0.f};                                               \
    cc = __builtin_amdgcn_mfma_f32_16x16x32_bf16(wra_h, ch_.v, cc, 0, 0, 0);    \
    cc = __builtin_amdgcn_mfma_f32_16x16x32_bf16(wra_h, cl_.v, cc, 0, 0, 0);    \
    cc = __builtin_amdgcn_mfma_f32_16x16x32_bf16(wra_l, ch_.v, cc, 0, 0, 0);    \
    ch_.f = pbh1; cl_.f = pbl1;                                                 \
    f32x4 cc2 = {0.f,0.f,0.f,0.f};                                              \
    cc2 = __builtin_amdgcn_mfma_f32_16x16x32_bf16(wra_h, ch_.v, cc2, 0, 0, 0);  \
    cc2 = __builtin_amdgcn_mfma_f32_16x16x32_bf16(wra_h, cl_.v, cc2, 0, 0, 0);  \
    cc2 = __builtin_amdgcn_mfma_f32_16x16x32_bf16(wra_l, ch_.v, cc2, 0, 0, 0);  \
    __builtin_amdgcn_s_setprio(0);                                              \
    { const int gg = g0;                                                        \
      float* cd = cstg + (BSEL)*4128 + (gg>>1)*32 + (gg&1)*16 + (l&15);         \
      _Pragma("unroll")                                                         \
      for (int rg = 0; rg < 4; rg++) cd[(4*(l>>4)+rg)*258] = cc[rg]; }          \
    { const int gg = g0 + 1;                                                    \
      float* cd = cstg + (BSEL)*4128 + (gg>>1)*32 + (gg&1)*16 + (l&15);         \
      _Pragma("unroll")                                                         \
      for (int rg = 0; rg < 4; rg++) cd[(4*(l>>4)+rg)*258] = cc2[rg]; } }

    // prologue: build r=0 into buf0, prefetch r=1
    LOADB(0);
    BUILD(0);
    LOADB(1);
    __syncthreads();

#pragma unroll 1
    for (int r = 0; r < 8; r++) {
        if (r < 7) {
            BUILD((r+1)&1);
            if (r < 6) LOADB(r+2);
        }

        // ---- P2: quad-j t2 in regs -> pack -> shfl swap -> A-frag capture ----
        {
            const float* c1b = stg1 + (r & 1) * 4128 + w * 258;
            float t0q=0.f, t1q=0.f, t2q=0.f, t3q=0.f;
#pragma unroll
            for (int i = 0; i < 8; i++) {
                const float cv = c1b[i * 32 + kP];
                t0q += hreg[i*4+0] * cv; t1q += hreg[i*4+1] * cv;
                t2q += hreg[i*4+2] * cv; t3q += hreg[i*4+3] * cv;
            }
            const u16 h0 = f2bf_bits(t0q), h1 = f2bf_bits(t1q),
                      h2 = f2bf_bits(t2q), h3 = f2bf_bits(t3q);
            const u16 q0 = f2bf_bits(t0q - bfbits2f(h0)), q1 = f2bf_bits(t1q - bfbits2f(h1)),
                      q2 = f2bf_bits(t2q - bfbits2f(h2)), q3 = f2bf_bits(t3q - bfbits2f(h3));
            const u32 th0 = (u32)h0 | ((u32)h1 << 16), th1 = (u32)h2 | ((u32)h3 << 16);
            const u32 tl0 = (u32)q0 | ((u32)q1 << 16), tl1 = (u32)q2 | ((u32)q3 << 16);
            const u32 ph0 = (u32)__shfl_xor((int)th0, 32);
            const u32 ph1 = (u32)__shfl_xor((int)th1, 32);
            const u32 pl0 = (u32)__shfl_xor((int)tl0, 32);
            const u32 pl1 = (u32)__shfl_xor((int)tl1, 32);
            const u32 a0 = jh ? ph0 : th0, a1 = jh ? ph1 : th1;
            const u32 a2 = jh ? th0 : ph0, a3 = jh ? th1 : ph1;
            const u32 b0 = jh ? pl0 : tl0, b1 = jh ? pl1 : tl1;
            const u32 b2 = jh ? tl0 : pl0, b3 = jh ? tl1 : pl1;
            if ((r & 1) == jh) {
                Afh0 = a0; Afh1 = a1; Afh2 = a2; Afh3 = a3;
                Afl0 = b0; Afl1 = b1; Afl2 = b2; Afl3 = b3;
            }
        }

        // ---- REPACK: cb2 staging -> B-frag capture (broadcast reads) ----
        {
            const float* c2b = stg2 + (r & 1) * 4128 + w * 258;
            const float v0 = c2b[0*32+kP], v1 = c2b[1*32+kP], v2 = c2b[2*32+kP],
                        v3 = c2b[3*32+kP], v4 = c2b[4*32+kP], v5 = c2b[5*32+kP],
                        v6 = c2b[6*32+kP], v7 = c2b[7*32+kP];
            const u16 e0 = f2bf_bits(v0), e1 = f2bf_bits(v1), e2 = f2bf_bits(v2),
                      e3 = f2bf_bits(v3), e4 = f2bf_bits(v4), e5 = f2bf_bits(v5),
                      e6 = f2bf_bits(v6), e7 = f2bf_bits(v7);
            const u16 f0 = f2bf_bits(v0 - bfbits2f(e0)), f1 = f2bf_bits(v1 - bfbits2f(e1)),
                      f2 = f2bf_bits(v2 - bfbits2f(e2)), f3 = f2bf_bits(v3 - bfbits2f(e3)),
                      f4 = f2bf_bits(v4 - bfbits2f(e4)), f5 = f2bf_bits(v5 - bfbits2f(e5)),
                      f6 = f2bf_bits(v6 - bfbits2f(e6)), f7 = f2bf_bits(v7 - bfbits2f(e7));
            if ((r & 1) == jh) {
                Bfh0 = (u32)e0 | ((u32)e1 << 16); Bfh1 = (u32)e2 | ((u32)e3 << 16);
                Bfh2 = (u32)e4 | ((u32)e5 << 16); Bfh3 = (u32)e6 | ((u32)e7 << 16);
                Bfl0 = (u32)f0 | ((u32)f1 << 16); Bfl1 = (u32)f2 | ((u32)f3 << 16);
                Bfl2 = (u32)f4 | ((u32)f5 << 16); Bfl3 = (u32)f6 | ((u32)f7 << 16);
            }
        }

        // ---- WINDOW at odd r: all-reg 32x32x16 MFMA (wave-private) ----
        if (r & 1) {
            U4Cast ua;
            ua.u[0]=Afh0; ua.u[1]=Afh1; ua.u[2]=Afh2; ua.u[3]=Afh3; const bf16x8 Ah = ua.v;
            ua.u[0]=Afl0; ua.u[1]=Afl1; ua.u[2]=Afl2; ua.u[3]=Afl3; const bf16x8 Al = ua.v;
            ua.u[0]=Bfh0; ua.u[1]=Bfh1; ua.u[2]=Bfh2; ua.u[3]=Bfh3; const bf16x8 Bh = ua.v;
            ua.u[0]=Bfl0; ua.u[1]=Bfl1; ua.u[2]=Bfl2; ua.u[3]=Bfl3; const bf16x8 Bl = ua.v;
            accw = __builtin_amdgcn_mfma_f32_32x32x16_bf16(Ah, Bh, accw, 0, 0, 0);
            accw = __builtin_amdgcn_mfma_f32_32x32x16_bf16(Ah, Bl, accw, 0, 0, 0);
            accw = __builtin_amdgcn_mfma_f32_32x32x16_bf16(Al, Bh, accw, 0, 0, 0);
        }
        __syncthreads();   // staging dbuf protection (one barrier per r)
    }
#undef LOADB
#undef BUILD

    // ---- epilogue: gelu + split -> gA frags, chunk-swizzled g(c)=c^((c>>4)&3) ----
    {
        const int l2  = (kP >> 3) * 16 + w;
        const int sl2 = l2 ^ ((l2 >> 4) & 3);      // involution, spreads bank quads
#pragma unroll
        for (int rg = 0; rg < 16; rg++) {
            const int k = (rg & 3) + 8 * (rg >> 2) + 4 * jh;   // C/D row = out k-index
            const float v = gelu_exact(accw[rg]);
            const u16 hbits = f2bf_bits(v);
            const u16 lbits = f2bf_bits(v - bfbits2f(hbits));
            const int idx = (k * 64 + sl2) * 8 + (kP & 7);
            gAh[idx] = hbits; gAl[idx] = lbits;
        }
    }
    __syncthreads();

    // ---- down-proj: y[16][256] = g @ W + b ; ALL 16 waves, wave w owns n-group w ----
    {
        f32x4 dacc = {0.f,0.f,0.f,0.f};
        const int gl = l ^ ((l >> 4) & 3);         // read through the same involution
        const int wb = w * 16384 + l * 8;          // (ng*32+kc)*512 + l*8
#pragma unroll 2
        for (int kc = 0; kc < 32; kc++) {
            cu.f = *(const float4*)(gAh + (kc * 64 + gl) * 8); const bf16x8 ah = cu.v;
            cu.f = *(const float4*)(gAl + (kc * 64 + gl) * 8); const bf16x8 al = cu.v;
            ABCast c0, c1;
            c0.f = *(const float4*)(wfh + wb + kc * 512); const bf16x8 bh = c0.v;
            c1.f = *(const float4*)(wfl + wb + kc * 512); const bf16x8 bl = c1.v;
            dacc = __builtin_amdgcn_mfma_f32_16x16x32_bf16(ah, bh, dacc, 0, 0, 0);
            dacc = __builtin_amdgcn_mfma_f32_16x16x32_bf16(ah, bl, dacc, 0, 0, 0);
            dacc = __builtin_amdgcn_mfma_f32_16x16x32_bf16(al, bh, dacc, 0, 0, 0);
        }
        const int n0 = w * 16 + (l & 15);
        const float b0 = bias[n0];
        const int tb = t0 + 4 * (l >> 4);
#pragma unroll
        for (int rg = 0; rg < 4; rg++)
            y[(tb + rg) * 256 + n0] = dacc[rg] + b0;
    }
}

extern "C" void kernel_launch(void* const* d_in, const int* in_sizes, int n_in,
                              void* d_out, int out_size, void* d_ws, size_t ws_size,
                              hipStream_t stream)
{
    const float* x    = (const float*)d_in[0];
    const int*   nidx = (const int*)  d_in[1];
    const float* nw   = (const float*)d_in[2];
    const float* rec  = (const float*)d_in[3];
    const float* A1   = (const float*)d_in[4];
    const float* A2   = (const float*)d_in[5];
    const float* B1   = (const float*)d_in[6];
    const float* B2   = (const float*)d_in[7];
    const float* Wd   = (const float*)d_in[8];
    const float* bd   = (const float*)d_in[9];
    float* y  = (float*)d_out;

    float* wr  = (float*)d_ws;                   // 8192*32 f32
    float* h   = wr + 8192 * 32;                 // 8192*64 f32
    u16* wrAh  = (u16*)(h + 8192 * 64);          // 262144 u16
    u16* wrAl  = wrAh + 262144;
    u16* b1h   = wrAl + 262144;                  // 65536 u16 each
    u16* b1l   = b1h + 65536;
    u16* b2h   = b1l + 65536;
    u16* b2l   = b2h + 65536;
    u16* wfh   = b2l + 65536;                    // 262144 u16 each
    u16* wfl   = wfh + 262144;

    k_route <<<128,  64,   0, stream>>>(nidx, nw, rec, wr, wrAh, wrAl);
    k_prep  <<<192,  256,  0, stream>>>(B1, B2, b1h, b1l, b2h, b2l, Wd, wfh, wfl);
    k_stageA<<<1024, 512,  0, stream>>>(x, wr, A1, A2, h);
    k_fusedB<<<512,  1024, 0, stream>>>(h, wrAh, wrAl, b1h, b1l, b2h, b2l, wfh, wfl, bd, y);
}